// Round 11
// baseline (394.377 us; speedup 1.0000x reference)
//
#include <hip/hip_runtime.h>

// ---------------------------------------------------------------------------
// G_CAM_Module: out = gamma * (GA @ x) + x, where GA comes from a chain of
// softmaxed 64x64 Gram matrices of x and g.
//
//   A) gram_kernel  : partial Grams via MFMA f16, BARRIER-FREE: fragments
//                     read directly from global f32 (2x dwordx4 + cvt_pkrtz),
//                     no LDS. L1/L2 serve the 4-way cross-wave row reuse.
//                     R5-R10 showed the stage/barrier convoy (not BW, not
//                     occupancy, not MLP) capped every LDS-staged variant.
//   B) reduce_kernel: sum 64 chunk-partials -> ex[b], eg[b]
//   C) chain_kernel : softmax chain -> M = gamma*GA   (no identity; tiny fp32)
//   D) apply_kernel : out[b] = M[b] @ x_b + x_b via MFMA f16 (fp32 residual)
// ---------------------------------------------------------------------------

typedef _Float16 h8 __attribute__((ext_vector_type(8)));
typedef float    f4 __attribute__((ext_vector_type(4)));
typedef __fp16   p2 __attribute__((ext_vector_type(2)));   // cvt_pkrtz result
typedef unsigned int u4v __attribute__((ext_vector_type(4)));

#define NB 16
#define NC 64
#define NPIX 65536
#define GRAM_CHUNK 1024                 // pixels per gram block
#define PASS_PX 128                     // pixels per "pass" (loop tiling only)
#define NPASS (GRAM_CHUNK / PASS_PX)    // 8
#define NCHUNK (NPIX / GRAM_CHUNK)      // 64

#define AP_NPX 256                      // apply: pixels per block
#define XT_ROW 72                       // apply: xT row stride in halves (144B)

__device__ __forceinline__ unsigned int pk(float a, float b) {
    p2 v = __builtin_amdgcn_cvt_pkrtz(a, b);
    return __builtin_bit_cast(unsigned int, v);
}

// load 8 consecutive f32 at p (16B-aligned), convert to h8 fragment
__device__ __forceinline__ h8 ldfrag(const float* p) {
    f4 lo = *(const f4*)p;
    f4 hi = *(const f4*)(p + 4);
    u4v u;
    u.x = pk(lo.x, lo.y); u.y = pk(lo.z, lo.w);
    u.z = pk(hi.x, hi.y); u.w = pk(hi.z, hi.w);
    return __builtin_bit_cast(h8, u);
}

// ---- Kernel A: partial Gram matrices via MFMA, barrier-free ---------------
// grid (64, 16, 2): chunk, batch, which-matrix. 256 threads = 4 waves; wave w
// computes the 16x64 slab rows [16w, 16w+16). Fragments come straight from
// global memory; the 4-way B-row reuse across waves is L1-resident (a pass's
// working set = 64 rows x 512B = 32KB = L1 size).
__global__ __launch_bounds__(256) void gram_kernel(
    const float* __restrict__ x, const float* __restrict__ g,
    float* __restrict__ part)
{
    const int tid = threadIdx.x;
    const int mtx = blockIdx.z;
    const float* src = (mtx ? g : x)
        + (size_t)blockIdx.y * NC * NPIX + (size_t)blockIdx.x * GRAM_CHUNK;

    const int w     = tid >> 6;
    const int lane  = tid & 63;
    const int l15   = lane & 15;
    const int khalf = lane >> 4;      // 0..3 -> 8-px k-group

    // per-lane row base pointers (row stride NPIX floats)
    const float* arow = src + (size_t)(w * 16 + l15) * NPIX;   // A rows
    const float* brow[4];
    #pragma unroll
    for (int cb = 0; cb < 4; ++cb)
        brow[cb] = src + (size_t)(cb * 16 + l15) * NPIX;

    f4 acc[4];
    #pragma unroll
    for (int cb = 0; cb < 4; ++cb) acc[cb] = (f4){0.f, 0.f, 0.f, 0.f};

    for (int pass = 0; pass < NPASS; ++pass) {
        #pragma unroll
        for (int ks = 0; ks < 4; ++ks) {
            const int px = pass * PASS_PX + ks * 32 + khalf * 8;
            h8 a = ldfrag(arow + px);
            #pragma unroll
            for (int cb = 0; cb < 4; ++cb) {
                h8 bf;
                if (cb == w) bf = a;              // wave-uniform branch (CSE)
                else         bf = ldfrag(brow[cb] + px);
                acc[cb] = __builtin_amdgcn_mfma_f32_16x16x32_f16(a, bf, acc[cb], 0, 0, 0);
            }
        }
    }

    float* po = part + (((size_t)blockIdx.x * NB + blockIdx.y) * 2 + mtx) * 4096;
    #pragma unroll
    for (int cb = 0; cb < 4; ++cb)
        #pragma unroll
        for (int r = 0; r < 4; ++r)
            po[(w * 16 + khalf * 4 + r) * 64 + cb * 16 + l15] = acc[cb][r];
}

// ---- Kernel B: reduce 64 chunk-partials -> ex, eg -------------------------
__global__ __launch_bounds__(256) void reduce_kernel(
    const float* __restrict__ part, float* __restrict__ ex, float* __restrict__ eg)
{
    const int idx = blockIdx.x * 256 + threadIdx.x;
    const int bm = idx >> 12;          // b*2 + m
    const int cd = idx & 4095;
    float s = 0.f;
    #pragma unroll 8
    for (int ch = 0; ch < NCHUNK; ++ch)
        s += part[(size_t)ch * (NB * 2 * 4096) + (size_t)bm * 4096 + cd];
    float* dst = (bm & 1) ? eg : ex;
    dst[(bm >> 1) * 4096 + cd] = s;
}

// ---- Kernel C: softmax chain -> M = gamma*GA (no identity) ----------------
__global__ __launch_bounds__(256) void chain_kernel(
    const float* __restrict__ ex, const float* __restrict__ eg,
    const float* __restrict__ gammap, float* __restrict__ M)
{
    __shared__ float A1[64][68];
    __shared__ float A2[64][68];
    __shared__ float red[64][4];

    const int b = blockIdx.x;
    const int tid = threadIdx.x;

    if (tid < 64) {
        const int c = tid;
        float r[64];
        #pragma unroll
        for (int d = 0; d < 64; ++d) r[d] = ex[b * 4096 + c * 64 + d];
        float mx = r[0];
        #pragma unroll
        for (int d = 1; d < 64; ++d) mx = fmaxf(mx, r[d]);
        float s = 0.f;
        #pragma unroll
        for (int d = 0; d < 64; ++d) { r[d] = expf(r[d] - mx); s += r[d]; }
        float inv = 1.f / s;
        #pragma unroll
        for (int d = 0; d < 64; ++d) A1[c][d] = r[d] * inv;

        #pragma unroll
        for (int d = 0; d < 64; ++d) r[d] = eg[b * 4096 + c * 64 + d];
        mx = r[0];
        #pragma unroll
        for (int d = 1; d < 64; ++d) mx = fmaxf(mx, r[d]);
        s = 0.f;
        #pragma unroll
        for (int d = 0; d < 64; ++d) { r[d] = expf(r[d] - mx); s += r[d]; }
        inv = 1.f / s;
        #pragma unroll
        for (int d = 0; d < 64; ++d) A2[c][d] = r[d] * inv;
    }
    __syncthreads();

    const int c = tid >> 2, sq = tid & 3;
    float ge[16];
    #pragma unroll
    for (int k = 0; k < 16; ++k) ge[k] = 0.f;
    for (int d = 0; d < 64; ++d) {
        float a = A1[c][d];
        const float* row = &A2[d][sq * 16];
        #pragma unroll
        for (int k = 0; k < 16; ++k) ge[k] = fmaf(a, row[k], ge[k]);
    }

    float mx = ge[0];
    #pragma unroll
    for (int k = 1; k < 16; ++k) mx = fmaxf(mx, ge[k]);
    red[c][sq] = mx;
    __syncthreads();
    float gm = fmaxf(fmaxf(red[c][0], red[c][1]), fmaxf(red[c][2], red[c][3]));
    __syncthreads();

    float gen[16];
    #pragma unroll
    for (int k = 0; k < 16; ++k) gen[k] = gm - ge[k];
    float mx2 = gen[0];
    #pragma unroll
    for (int k = 1; k < 16; ++k) mx2 = fmaxf(mx2, gen[k]);
    red[c][sq] = mx2;
    __syncthreads();
    float m2 = fmaxf(fmaxf(red[c][0], red[c][1]), fmaxf(red[c][2], red[c][3]));
    __syncthreads();

    float p[16];
    float s = 0.f;
    #pragma unroll
    for (int k = 0; k < 16; ++k) { p[k] = expf(gen[k] - m2); s += p[k]; }
    red[c][sq] = s;
    __syncthreads();
    float S = red[c][0] + red[c][1] + red[c][2] + red[c][3];

    float gam = gammap[0];
    float invS = 1.f / S;
    #pragma unroll
    for (int k = 0; k < 16; ++k) {
        int e = sq * 16 + k;
        M[b * 4096 + c * 64 + e] = gam * p[k] * invS;   // NO +I: residual in apply
    }
}

// ---- Kernel D: out[b] = M[b] @ x[b] + x[b] via MFMA ------------------------
__global__ __launch_bounds__(256) void apply_kernel(
    const float* __restrict__ x, const float* __restrict__ M,
    float* __restrict__ out)
{
    __shared__ __align__(16) _Float16 xT[AP_NPX * XT_ROW];   // 36864 B
    __shared__ __align__(16) _Float16 Ml[64 * XT_ROW];       //  9216 B

    const int tid = threadIdx.x;
    const int b = blockIdx.y;
    const int n0 = blockIdx.x * AP_NPX;
    const float* xb = x + (size_t)b * NC * NPIX + n0;

    #pragma unroll
    for (int it = 0; it < 8; ++it) {
        int e = it * 256 + tid;
        int q  = e & 63;          // f4 col (4 pixels)
        int dp = e >> 6;          // d-pair 0..31
        f4 va = *(const f4*)(xb + (size_t)(2 * dp)     * NPIX + q * 4);
        f4 vb = *(const f4*)(xb + (size_t)(2 * dp + 1) * NPIX + q * 4);
        #pragma unroll
        for (int j = 0; j < 4; ++j) {
            float aj = (j == 0) ? va.x : (j == 1) ? va.y : (j == 2) ? va.z : va.w;
            float bj = (j == 0) ? vb.x : (j == 1) ? vb.y : (j == 2) ? vb.z : vb.w;
            *reinterpret_cast<unsigned int*>(&xT[(q * 4 + j) * XT_ROW + 2 * dp]) = pk(aj, bj);
        }
    }
    const float* Mb = M + b * 4096;
    #pragma unroll
    for (int it = 0; it < 4; ++it) {
        int e = it * 256 + tid;
        int c  = e >> 4;
        int qq = e & 15;
        f4 mv = *(const f4*)(Mb + c * 64 + qq * 4);
        *reinterpret_cast<unsigned int*>(&Ml[c * XT_ROW + qq * 4])     = pk(mv.x, mv.y);
        *reinterpret_cast<unsigned int*>(&Ml[c * XT_ROW + qq * 4 + 2]) = pk(mv.z, mv.w);
    }
    __syncthreads();

    const int w    = tid >> 6;
    const int lane = tid & 63;
    const int l15  = lane & 15;
    const int kh   = lane >> 4;

    h8 bfrag[4][2];
    #pragma unroll
    for (int nb = 0; nb < 4; ++nb)
        #pragma unroll
        for (int ks = 0; ks < 2; ++ks)
            bfrag[nb][ks] = *reinterpret_cast<const h8*>(
                &xT[(w * 64 + nb * 16 + l15) * XT_ROW + ks * 32 + kh * 8]);

    f4 acc[4][4];   // [cb][nb]
    #pragma unroll
    for (int cb = 0; cb < 4; ++cb)
        #pragma unroll
        for (int nb = 0; nb < 4; ++nb) acc[cb][nb] = (f4){0.f, 0.f, 0.f, 0.f};

    #pragma unroll
    for (int cb = 0; cb < 4; ++cb) {
        #pragma unroll
        for (int ks = 0; ks < 2; ++ks) {
            h8 a = *reinterpret_cast<const h8*>(
                &Ml[(cb * 16 + l15) * XT_ROW + ks * 32 + kh * 8]);
            #pragma unroll
            for (int nb = 0; nb < 4; ++nb)
                acc[cb][nb] = __builtin_amdgcn_mfma_f32_16x16x32_f16(a, bfrag[nb][ks], acc[cb][nb], 0, 0, 0);
        }
    }

    const size_t base = (size_t)b * NC * NPIX + n0 + w * 64;
    #pragma unroll
    for (int cb = 0; cb < 4; ++cb) {
        #pragma unroll
        for (int r = 0; r < 4; ++r) {
            const int row = cb * 16 + kh * 4 + r;
            #pragma unroll
            for (int nb = 0; nb < 4; ++nb) {
                size_t idx = base + (size_t)row * NPIX + nb * 16 + l15;
                out[idx] = acc[cb][nb][r] + x[idx];
            }
        }
    }
}

extern "C" void kernel_launch(void* const* d_in, const int* in_sizes, int n_in,
                              void* d_out, int out_size, void* d_ws, size_t ws_size,
                              hipStream_t stream) {
    const float* x     = (const float*)d_in[0];
    const float* g     = (const float*)d_in[1];
    const float* gamma = (const float*)d_in[2];
    float* out = (float*)d_out;
    float* ws  = (float*)d_ws;

    float* ex = ws;                  // 16*4096 floats
    float* eg = ws + NB * 4096;      // 16*4096 floats
    float* M  = ws + 2 * NB * 4096;  // 16*4096 floats

    // d_out doubles as scratch for the 33.5 MB gram partials; apply_kernel
    // fully overwrites d_out afterwards (stream-ordered), so this is safe.
    float* part = out;

    gram_kernel<<<dim3(NCHUNK, NB, 2), 256, 0, stream>>>(x, g, part);
    reduce_kernel<<<512, 256, 0, stream>>>(part, ex, eg);
    chain_kernel<<<NB, 256, 0, stream>>>(ex, eg, gamma, M);
    apply_kernel<<<dim3(NPIX / AP_NPX, NB), 256, 0, stream>>>(x, M, out);
}

// Round 12
// 266.612 us; speedup vs baseline: 1.4792x; 1.4792x over previous
//
#include <hip/hip_runtime.h>

// ---------------------------------------------------------------------------
// G_CAM_Module: out = gamma * (GA @ x) + x, where GA comes from a chain of
// softmaxed 64x64 Gram matrices of x and g.
//
//   A) gram_kernel  : partial Grams via MFMA f16, "apply-clone": 4096 blocks,
//                     512 threads, ONE staging batch (16 f4 loads/thread,
//                     pinned), ONE barrier, 32 MFMA/wave, 16KB partial out.
//                     launch_bounds(512,4) keeps the VGPR cap at 128 so the
//                     allocator cannot serialize the staging loads (R11:
//                     VGPR=28 -> 1 load in flight; R9: 32).
//   B) reduce_kernel: sum 128 chunk-partials -> ex[b], eg[b]
//   C) chain_kernel : softmax chain -> M = gamma*GA   (no identity; tiny fp32)
//   D) apply_kernel : out[b] = M[b] @ x_b + x_b via MFMA f16 (fp32 residual)
// ---------------------------------------------------------------------------

typedef _Float16 h8 __attribute__((ext_vector_type(8)));
typedef float    f4 __attribute__((ext_vector_type(4)));
typedef __fp16   p2 __attribute__((ext_vector_type(2)));   // cvt_pkrtz result
typedef unsigned long long ull;

#define NB 16
#define NC 64
#define NPIX 65536
#define GRAM_CHUNK 512                  // pixels per gram block
#define NCHUNK (NPIX / GRAM_CHUNK)      // 128
#define ROW_H 520                       // LDS row stride, halves (1040 B)
#define LDS_H (64 * ROW_H + 64)         // 33344 halves = 66688 B

#define AP_NPX 256                      // apply: pixels per block
#define XT_ROW 72                       // apply: xT row stride in halves (144B)

__device__ __forceinline__ int rowbase_h(int c) {
    return c * ROW_H + (c >> 3) * 8;
}

__device__ __forceinline__ unsigned int pk(float a, float b) {
    p2 v = __builtin_amdgcn_cvt_pkrtz(a, b);
    return __builtin_bit_cast(unsigned int, v);
}

// ---- Kernel A: partial Gram matrices via MFMA, apply-clone ----------------
// grid (128, 16, 2): chunk, batch, which-matrix. 512 threads = 8 waves.
// Wave w: row-block wr = w>>1 (A rows), col-half wc = w&1 (B rows).
// Stage all 64ch x 512px once -> 1 barrier -> 8 K-steps x 2 MFMAs.
__global__ __launch_bounds__(512, 4) void gram_kernel(
    const float* __restrict__ x, const float* __restrict__ g,
    float* __restrict__ part)
{
    __shared__ __align__(16) _Float16 buf[LDS_H];   // 66688 B

    const int tid = threadIdx.x;
    const int mtx = blockIdx.z;
    const float* src = (mtx ? g : x)
        + (size_t)blockIdx.y * NC * NPIX + (size_t)blockIdx.x * GRAM_CHUNK;

    // staging coords: q fixed per thread, row advances 4 per batch-slot
    const int sq = tid & 127;          // f4 index within 512 px
    const int sr = tid >> 7;           // base row 0..3 (+4 per it)

    // ---- single staging batch: 16 f4 loads, pinned live, then cvt+write ----
    f4 t0, t1, t2, t3, t4, t5, t6, t7, t8, t9, t10, t11, t12, t13, t14, t15;
    {
        const float* p = src + (size_t)sr * NPIX + sq * 4;
        const size_t rs = 4 * (size_t)NPIX;
        t0  = *(const f4*)(p + 0 * rs);   t1  = *(const f4*)(p + 1 * rs);
        t2  = *(const f4*)(p + 2 * rs);   t3  = *(const f4*)(p + 3 * rs);
        t4  = *(const f4*)(p + 4 * rs);   t5  = *(const f4*)(p + 5 * rs);
        t6  = *(const f4*)(p + 6 * rs);   t7  = *(const f4*)(p + 7 * rs);
        t8  = *(const f4*)(p + 8 * rs);   t9  = *(const f4*)(p + 9 * rs);
        t10 = *(const f4*)(p + 10 * rs);  t11 = *(const f4*)(p + 11 * rs);
        t12 = *(const f4*)(p + 12 * rs);  t13 = *(const f4*)(p + 13 * rs);
        t14 = *(const f4*)(p + 14 * rs);  t15 = *(const f4*)(p + 15 * rs);
    }
    // pin all 16 results live -> loads issue as one cluster, one drain
    asm volatile("" : "+v"(t0), "+v"(t1), "+v"(t2), "+v"(t3));
    asm volatile("" : "+v"(t4), "+v"(t5), "+v"(t6), "+v"(t7));
    asm volatile("" : "+v"(t8), "+v"(t9), "+v"(t10), "+v"(t11));
    asm volatile("" : "+v"(t12), "+v"(t13), "+v"(t14), "+v"(t15));

    #define CVW(T, IT) { \
        ull h = (ull)pk(T.x, T.y) | ((ull)pk(T.z, T.w) << 32); \
        *reinterpret_cast<ull*>(&buf[rowbase_h((IT) * 4 + sr) + 4 * sq]) = h; }
    CVW(t0, 0)  CVW(t1, 1)  CVW(t2, 2)  CVW(t3, 3)
    CVW(t4, 4)  CVW(t5, 5)  CVW(t6, 6)  CVW(t7, 7)
    CVW(t8, 8)  CVW(t9, 9)  CVW(t10, 10) CVW(t11, 11)
    CVW(t12, 12) CVW(t13, 13) CVW(t14, 14) CVW(t15, 15)
    #undef CVW

    __syncthreads();   // the ONLY barrier

    // ---- consume: wave (wr, wc), 16 K-steps x 2 MFMAs ----
    const int w     = tid >> 6;
    const int lane  = tid & 63;
    const int l15   = lane & 15;
    const int khalf = lane >> 4;
    const int wr    = w >> 1;
    const int wc    = w & 1;
    const int abase_h = rowbase_h(wr * 16 + l15);
    const int bbase0  = rowbase_h((wc * 2 + 0) * 16 + l15);
    const int bbase1  = rowbase_h((wc * 2 + 1) * 16 + l15);

    f4 acc0 = (f4){0.f, 0.f, 0.f, 0.f};
    f4 acc1 = (f4){0.f, 0.f, 0.f, 0.f};

    #pragma unroll
    for (int ks = 0; ks < 16; ++ks) {
        int koff = ks * 32 + khalf * 8;
        h8 a  = *reinterpret_cast<const h8*>(&buf[abase_h + koff]);
        h8 b0 = *reinterpret_cast<const h8*>(&buf[bbase0 + koff]);
        h8 b1 = *reinterpret_cast<const h8*>(&buf[bbase1 + koff]);
        acc0 = __builtin_amdgcn_mfma_f32_16x16x32_f16(a, b0, acc0, 0, 0, 0);
        acc1 = __builtin_amdgcn_mfma_f32_16x16x32_f16(a, b1, acc1, 0, 0, 0);
    }

    float* po = part + (((size_t)blockIdx.x * NB + blockIdx.y) * 2 + mtx) * 4096;
    #pragma unroll
    for (int r = 0; r < 4; ++r) {
        po[(wr * 16 + khalf * 4 + r) * 64 + wc * 32 + 0 * 16 + l15] = acc0[r];
        po[(wr * 16 + khalf * 4 + r) * 64 + wc * 32 + 1 * 16 + l15] = acc1[r];
    }
}

// ---- Kernel B: reduce 128 chunk-partials -> ex, eg -------------------------
__global__ __launch_bounds__(256) void reduce_kernel(
    const float* __restrict__ part, float* __restrict__ ex, float* __restrict__ eg)
{
    const int idx = blockIdx.x * 256 + threadIdx.x;
    const int bm = idx >> 12;          // b*2 + m
    const int cd = idx & 4095;
    float s = 0.f;
    #pragma unroll 8
    for (int ch = 0; ch < NCHUNK; ++ch)
        s += part[(size_t)ch * (NB * 2 * 4096) + (size_t)bm * 4096 + cd];
    float* dst = (bm & 1) ? eg : ex;
    dst[(bm >> 1) * 4096 + cd] = s;
}

// ---- Kernel C: softmax chain -> M = gamma*GA (no identity) ----------------
__global__ __launch_bounds__(256) void chain_kernel(
    const float* __restrict__ ex, const float* __restrict__ eg,
    const float* __restrict__ gammap, float* __restrict__ M)
{
    __shared__ float A1[64][68];
    __shared__ float A2[64][68];
    __shared__ float red[64][4];

    const int b = blockIdx.x;
    const int tid = threadIdx.x;

    if (tid < 64) {
        const int c = tid;
        float r[64];
        #pragma unroll
        for (int d = 0; d < 64; ++d) r[d] = ex[b * 4096 + c * 64 + d];
        float mx = r[0];
        #pragma unroll
        for (int d = 1; d < 64; ++d) mx = fmaxf(mx, r[d]);
        float s = 0.f;
        #pragma unroll
        for (int d = 0; d < 64; ++d) { r[d] = expf(r[d] - mx); s += r[d]; }
        float inv = 1.f / s;
        #pragma unroll
        for (int d = 0; d < 64; ++d) A1[c][d] = r[d] * inv;

        #pragma unroll
        for (int d = 0; d < 64; ++d) r[d] = eg[b * 4096 + c * 64 + d];
        mx = r[0];
        #pragma unroll
        for (int d = 1; d < 64; ++d) mx = fmaxf(mx, r[d]);
        s = 0.f;
        #pragma unroll
        for (int d = 0; d < 64; ++d) { r[d] = expf(r[d] - mx); s += r[d]; }
        inv = 1.f / s;
        #pragma unroll
        for (int d = 0; d < 64; ++d) A2[c][d] = r[d] * inv;
    }
    __syncthreads();

    const int c = tid >> 2, sq = tid & 3;
    float ge[16];
    #pragma unroll
    for (int k = 0; k < 16; ++k) ge[k] = 0.f;
    for (int d = 0; d < 64; ++d) {
        float a = A1[c][d];
        const float* row = &A2[d][sq * 16];
        #pragma unroll
        for (int k = 0; k < 16; ++k) ge[k] = fmaf(a, row[k], ge[k]);
    }

    float mx = ge[0];
    #pragma unroll
    for (int k = 1; k < 16; ++k) mx = fmaxf(mx, ge[k]);
    red[c][sq] = mx;
    __syncthreads();
    float gm = fmaxf(fmaxf(red[c][0], red[c][1]), fmaxf(red[c][2], red[c][3]));
    __syncthreads();

    float gen[16];
    #pragma unroll
    for (int k = 0; k < 16; ++k) gen[k] = gm - ge[k];
    float mx2 = gen[0];
    #pragma unroll
    for (int k = 1; k < 16; ++k) mx2 = fmaxf(mx2, gen[k]);
    red[c][sq] = mx2;
    __syncthreads();
    float m2 = fmaxf(fmaxf(red[c][0], red[c][1]), fmaxf(red[c][2], red[c][3]));
    __syncthreads();

    float p[16];
    float s = 0.f;
    #pragma unroll
    for (int k = 0; k < 16; ++k) { p[k] = expf(gen[k] - m2); s += p[k]; }
    red[c][sq] = s;
    __syncthreads();
    float S = red[c][0] + red[c][1] + red[c][2] + red[c][3];

    float gam = gammap[0];
    float invS = 1.f / S;
    #pragma unroll
    for (int k = 0; k < 16; ++k) {
        int e = sq * 16 + k;
        M[b * 4096 + c * 64 + e] = gam * p[k] * invS;   // NO +I: residual in apply
    }
}

// ---- Kernel D: out[b] = M[b] @ x[b] + x[b] via MFMA ------------------------
__global__ __launch_bounds__(256) void apply_kernel(
    const float* __restrict__ x, const float* __restrict__ M,
    float* __restrict__ out)
{
    __shared__ __align__(16) _Float16 xT[AP_NPX * XT_ROW];   // 36864 B
    __shared__ __align__(16) _Float16 Ml[64 * XT_ROW];       //  9216 B

    const int tid = threadIdx.x;
    const int b = blockIdx.y;
    const int n0 = blockIdx.x * AP_NPX;
    const float* xb = x + (size_t)b * NC * NPIX + n0;

    #pragma unroll
    for (int it = 0; it < 8; ++it) {
        int e = it * 256 + tid;
        int q  = e & 63;          // f4 col (4 pixels)
        int dp = e >> 6;          // d-pair 0..31
        f4 va = *(const f4*)(xb + (size_t)(2 * dp)     * NPIX + q * 4);
        f4 vb = *(const f4*)(xb + (size_t)(2 * dp + 1) * NPIX + q * 4);
        #pragma unroll
        for (int j = 0; j < 4; ++j) {
            float aj = (j == 0) ? va.x : (j == 1) ? va.y : (j == 2) ? va.z : va.w;
            float bj = (j == 0) ? vb.x : (j == 1) ? vb.y : (j == 2) ? vb.z : vb.w;
            *reinterpret_cast<unsigned int*>(&xT[(q * 4 + j) * XT_ROW + 2 * dp]) = pk(aj, bj);
        }
    }
    const float* Mb = M + b * 4096;
    #pragma unroll
    for (int it = 0; it < 4; ++it) {
        int e = it * 256 + tid;
        int c  = e >> 4;
        int qq = e & 15;
        f4 mv = *(const f4*)(Mb + c * 64 + qq * 4);
        *reinterpret_cast<unsigned int*>(&Ml[c * XT_ROW + qq * 4])     = pk(mv.x, mv.y);
        *reinterpret_cast<unsigned int*>(&Ml[c * XT_ROW + qq * 4 + 2]) = pk(mv.z, mv.w);
    }
    __syncthreads();

    const int w    = tid >> 6;
    const int lane = tid & 63;
    const int l15  = lane & 15;
    const int kh   = lane >> 4;

    h8 bfrag[4][2];
    #pragma unroll
    for (int nb = 0; nb < 4; ++nb)
        #pragma unroll
        for (int ks = 0; ks < 2; ++ks)
            bfrag[nb][ks] = *reinterpret_cast<const h8*>(
                &xT[(w * 64 + nb * 16 + l15) * XT_ROW + ks * 32 + kh * 8]);

    f4 acc[4][4];   // [cb][nb]
    #pragma unroll
    for (int cb = 0; cb < 4; ++cb)
        #pragma unroll
        for (int nb = 0; nb < 4; ++nb) acc[cb][nb] = (f4){0.f, 0.f, 0.f, 0.f};

    #pragma unroll
    for (int cb = 0; cb < 4; ++cb) {
        #pragma unroll
        for (int ks = 0; ks < 2; ++ks) {
            h8 a = *reinterpret_cast<const h8*>(
                &Ml[(cb * 16 + l15) * XT_ROW + ks * 32 + kh * 8]);
            #pragma unroll
            for (int nb = 0; nb < 4; ++nb)
                acc[cb][nb] = __builtin_amdgcn_mfma_f32_16x16x32_f16(a, bfrag[nb][ks], acc[cb][nb], 0, 0, 0);
        }
    }

    const size_t base = (size_t)b * NC * NPIX + n0 + w * 64;
    #pragma unroll
    for (int cb = 0; cb < 4; ++cb) {
        #pragma unroll
        for (int r = 0; r < 4; ++r) {
            const int row = cb * 16 + kh * 4 + r;
            #pragma unroll
            for (int nb = 0; nb < 4; ++nb) {
                size_t idx = base + (size_t)row * NPIX + nb * 16 + l15;
                out[idx] = acc[cb][nb][r] + x[idx];
            }
        }
    }
}

extern "C" void kernel_launch(void* const* d_in, const int* in_sizes, int n_in,
                              void* d_out, int out_size, void* d_ws, size_t ws_size,
                              hipStream_t stream) {
    const float* x     = (const float*)d_in[0];
    const float* g     = (const float*)d_in[1];
    const float* gamma = (const float*)d_in[2];
    float* out = (float*)d_out;
    float* ws  = (float*)d_ws;

    float* ex = ws;                  // 16*4096 floats
    float* eg = ws + NB * 4096;      // 16*4096 floats
    float* M  = ws + 2 * NB * 4096;  // 16*4096 floats

    // d_out doubles as scratch for the 67 MB gram partials; apply_kernel
    // fully overwrites d_out afterwards (stream-ordered), so this is safe.
    float* part = out;

    gram_kernel<<<dim3(NCHUNK, NB, 2), 512, 0, stream>>>(x, g, part);
    reduce_kernel<<<512, 256, 0, stream>>>(part, ex, eg);
    chain_kernel<<<NB, 256, 0, stream>>>(ex, eg, gamma, M);
    apply_kernel<<<dim3(NPIX / AP_NPX, NB), 256, 0, stream>>>(x, M, out);
}